// Round 17
// baseline (256.321 us; speedup 1.0000x reference)
//
#include <hip/hip_runtime.h>
#include <cstdint>
#include <cstddef>

typedef unsigned short u16;
typedef __attribute__((ext_vector_type(8))) __bf16 bf16x8;   // MFMA A/B operand
typedef __attribute__((ext_vector_type(4))) float floatx4;   // MFMA C/D operand

// dims
#define T_DIM   512
#define B_SZ    8
#define ROWS    4096      // T*B
#define OBS_D   256
#define D_IN    2048
#define NHEAD   16
#define NSTATE  64
#define PDIM    128
#define NUNITS  256
#define NACT    64
#define NSEG    4
#define SEGT    128       // T_DIM / NSEG
#define SLOT    (B_SZ * NHEAD * PDIM * NSTATE)   // 1048576 elems per seg-state slot
#define BCSTR   2176      // BCm row stride: B(1024) | C(1024) | dtraw(16) | pad(112) = 17 x 128

__host__ __device__ __forceinline__ float bf2f(u16 u) {
    union { uint32_t i; float f; } v; v.i = ((uint32_t)u) << 16; return v.f;
}
__host__ __device__ __forceinline__ u16 f2bf(float f) {
    union { float f; uint32_t i; } v; v.f = f;
    uint32_t r = v.i + 0x7FFFu + ((v.i >> 16) & 1u);
    return (u16)(r >> 16);
}

// async 16B/lane global->LDS (m97 pattern). lds ptr must be wave-uniform.
__device__ __forceinline__ void glds16(const u16* g, u16* l) {
    __builtin_amdgcn_global_load_lds(
        (__attribute__((address_space(1))) void*)g,
        (__attribute__((address_space(3))) void*)l, 16, 0, 0);
}

// ---------------- harness-required symbol (zero-work launch keeps it referenced) ----------------
__global__ __launch_bounds__(256) void ActorAgent_27625229647898_kernel(
        float* __restrict__ out, int n, float v) {
    for (int i = blockIdx.x * 256 + threadIdx.x; i < n; i += gridDim.x * 256)
        out[i] = v;
}

// ---------------- prep: all weight converts + transposes in ONE launch ----------------
__global__ __launch_bounds__(256) void prep(const float* __restrict__ obs,
                                            const float* __restrict__ W_dt,
                                            const float* __restrict__ W_in,
                                            const float* __restrict__ W_B,
                                            const float* __restrict__ W_C,
                                            const float* __restrict__ W_yo,
                                            const float* __restrict__ W_head,
                                            u16* __restrict__ obsb,
                                            u16* __restrict__ WinT, u16* __restrict__ WBCT,
                                            u16* __restrict__ WyoT, u16* __restrict__ WheadT) {
    int bid = blockIdx.x;
    if (bid < 160) {
        const int NOBS = ROWS * OBS_D;             // 1048576
        const int NDT  = D_IN * NHEAD;             // 32768
        const int NZ   = 112 * D_IN;               // 229376 (zero pad rows 2064..2175)
        for (int i = bid * 256 + threadIdx.x; i < NOBS + NDT + NZ; i += 160 * 256) {
            if (i < NOBS) obsb[i] = f2bf(obs[i]);
            else if (i < NOBS + NDT) {
                int j = i - NOBS;                  // j = k*16 + n
                int k = j >> 4, n = j & 15;
                WBCT[(size_t)(2048 + n) * D_IN + k] = f2bf(W_dt[j]);
            } else {
                WBCT[(size_t)2064 * D_IN + (i - NOBS - NDT)] = 0;
            }
        }
        return;
    }
    bid -= 160;
    const float* src; u16* dst; int R, C, bx, by;
    if (bid < 512)       { src = W_in;   dst = WinT;   R = 256;  C = 2048; bx = bid & 63; by = bid >> 6; }
    else if (bid < 2560) { int i = bid - 512;  src = W_B;  dst = WBCT; R = 2048; C = 1024; bx = i & 31; by = i >> 5; }
    else if (bid < 4608) { int i = bid - 2560; src = W_C;  dst = WBCT + (size_t)1024 * 2048; R = 2048; C = 1024; bx = i & 31; by = i >> 5; }
    else if (bid < 5120) { int i = bid - 4608; src = W_yo; dst = WyoT; R = 2048; C = 256;  bx = i & 7;  by = i >> 3; }
    else                 { int i = bid - 5120; src = W_head; dst = WheadT; R = 256; C = 64; bx = i & 1; by = i >> 1; }
    __shared__ float t[32][33];
    int c0 = bx * 32, r0 = by * 32;
    int tx = threadIdx.x & 31, ty = threadIdx.x >> 5;
#pragma unroll
    for (int i = 0; i < 32; i += 8)
        t[ty + i][tx] = src[(size_t)(r0 + ty + i) * C + c0 + tx];
    __syncthreads();
#pragma unroll
    for (int i = 0; i < 32; i += 8)
        dst[(size_t)(c0 + ty + i) * R + r0 + tx] = f2bf(t[tx][ty + i]);
}

// ---------------- bt128: 128x128 bf16 MFMA GEMM, B^T (N,K), BK=32 glds staging ----------------
// Round-13 structure + XCD-aware tile swizzle: assuming round-robin wg->XCD,
// tiles are assigned n-major per XCD so each XCD's L2 holds ~2 contiguous
// B-slabs (~1.1 MB) -> B loads L2-resident -> shorter vmcnt drains.
// Requires gridDim.x == 32 and total blocks divisible by 8.
template <int ACT, int OUT_BF16, int HAS_BIAS>
__global__ __launch_bounds__(256) void gemm_bt128(const u16* __restrict__ A,
                                                  const u16* __restrict__ BT,
                                                  const float* __restrict__ bias,
                                                  void* __restrict__ Cout,
                                                  int M, int N, int K) {
    __shared__ __align__(16) u16 sA[128 * 32];
    __shared__ __align__(16) u16 sB[128 * 32];
    const int tid  = threadIdx.x;
    const int wave = tid >> 6, lane = tid & 63;
    const int quad = lane >> 4, lr = lane & 15;
    const int wm = wave & 1, wn = wave >> 1;
    // XCD swizzle: bid -> (xcd, slot) -> n-major global tile
    const int bid  = blockIdx.x + gridDim.x * blockIdx.y;
    const int nb   = gridDim.x * gridDim.y;
    const int g    = (bid & 7) * (nb >> 3) + (bid >> 3);
    const int m0 = (g & 31) * 128, n0 = (g >> 5) * 128;
    const int r0 = wave * 32 + (lane >> 2);   // staged row per lane
    const int kel = (lane & 3) * 8;           // k offset (u16) per lane

    floatx4 acc[4][4];
#pragma unroll
    for (int i = 0; i < 4; i++)
#pragma unroll
        for (int j = 0; j < 4; j++)
#pragma unroll
            for (int r = 0; r < 4; r++) acc[i][j][r] = 0.f;

    const u16* apg = A + (size_t)(m0 + r0) * K + kel;
    const u16* bpg = BT + (size_t)(n0 + r0) * K + kel;
    u16* lA0 = &sA[(wave * 32) * 32];
    u16* lA1 = &sA[(wave * 32 + 16) * 32];
    u16* lB0 = &sB[(wave * 32) * 32];
    u16* lB1 = &sB[(wave * 32 + 16) * 32];

    for (int k0 = 0; k0 < K; k0 += 32) {
        __syncthreads();   // previous iteration's LDS readers done
        glds16(apg + k0, lA0);
        glds16(apg + (size_t)16 * K + k0, lA1);
        glds16(bpg + k0, lB0);
        glds16(bpg + (size_t)16 * K + k0, lB1);
        __syncthreads();   // drain vmcnt -> LDS visible
        bf16x8 af[4], bfr[4];
#pragma unroll
        for (int i = 0; i < 4; i++)
            af[i] = *(const bf16x8*)&sA[(wm * 64 + i * 16 + lr) * 32 + quad * 8];
#pragma unroll
        for (int j = 0; j < 4; j++)
            bfr[j] = *(const bf16x8*)&sB[(wn * 64 + j * 16 + lr) * 32 + quad * 8];
#pragma unroll
        for (int i = 0; i < 4; i++)
#pragma unroll
            for (int j = 0; j < 4; j++)
                acc[i][j] = __builtin_amdgcn_mfma_f32_16x16x32_bf16(af[i], bfr[j], acc[i][j], 0, 0, 0);
    }
    // C/D layout: col = lane&15, row = quad*4 + reg
#pragma unroll
    for (int j = 0; j < 4; j++) {
        int col = n0 + wn * 64 + j * 16 + lr;
        float bvv = HAS_BIAS ? bias[col] : 0.f;
#pragma unroll
        for (int i = 0; i < 4; i++) {
#pragma unroll
            for (int r = 0; r < 4; r++) {
                int row = m0 + wm * 64 + i * 16 + quad * 4 + r;
                float v = acc[i][j][r] + bvv;
                if (ACT) v = fmaxf(v, 0.f);
                if (OUT_BF16) ((u16*)Cout)[(size_t)row * N + col] = f2bf(v);
                else          ((float*)Cout)[(size_t)row * N + col] = v;
            }
        }
    }
}

// ---------------- bt64: 64x64 bf16 MFMA GEMM, B^T layout, BK=64 glds staging ----------------
template <int ACT, int OUT_BF16>
__global__ __launch_bounds__(256) void gemm_bt64(const u16* __restrict__ A,
                                                 const u16* __restrict__ BT,
                                                 const float* __restrict__ bias,
                                                 void* __restrict__ Cout,
                                                 int M, int N, int K) {
    __shared__ __align__(16) u16 sA[64 * 64];  // 8 KB
    __shared__ __align__(16) u16 sB[64 * 64];
    const int tid  = threadIdx.x;
    const int wave = tid >> 6, lane = tid & 63;
    const int quad = lane >> 4, lr = lane & 15;
    const int m0 = blockIdx.x * 64, n0 = blockIdx.y * 64;
    const int srl = lane >> 3, sc = (lane & 7) * 8;

    floatx4 acc[4];
#pragma unroll
    for (int i = 0; i < 4; i++)
#pragma unroll
        for (int j = 0; j < 4; j++) acc[i][j] = 0.f;

    const u16* apg = A + (size_t)(m0 + wave * 16 + srl) * K + sc;
    const u16* bpg = BT + (size_t)(n0 + wave * 16 + srl) * K + sc;

    for (int k0 = 0; k0 < K; k0 += 64) {
        __syncthreads();
#pragma unroll
        for (int g = 0; g < 2; ++g) {
            glds16(apg + (size_t)(g * 8) * K + k0, &sA[(wave * 16 + g * 8) * 64]);
            glds16(bpg + (size_t)(g * 8) * K + k0, &sB[(wave * 16 + g * 8) * 64]);
        }
        __syncthreads();
#pragma unroll
        for (int ks = 0; ks < 2; ++ks) {
            bf16x8 af = *(const bf16x8*)&sA[(wave * 16 + lr) * 64 + ks * 32 + quad * 8];
#pragma unroll
            for (int nt = 0; nt < 4; nt++) {
                bf16x8 bf = *(const bf16x8*)&sB[(nt * 16 + lr) * 64 + ks * 32 + quad * 8];
                acc[nt] = __builtin_amdgcn_mfma_f32_16x16x32_bf16(af, bf, acc[nt], 0, 0, 0);
            }
        }
    }
#pragma unroll
    for (int nt = 0; nt < 4; nt++) {
        int col = n0 + nt * 16 + lr;
        float bvv = bias ? bias[col] : 0.f;
#pragma unroll
        for (int r = 0; r < 4; r++) {
            int row = m0 + wave * 16 + quad * 4 + r;
            float v = acc[nt][r] + bvv;
            if (ACT) v = fmaxf(v, 0.f);
            if (OUT_BF16) ((u16*)Cout)[(size_t)row * N + col] = f2bf(v);
            else          ((float*)Cout)[(size_t)row * N + col] = v;
        }
    }
}

// ---------------- dt_fix: softplus + decay from GEMM-produced dtraw ----------------
__global__ __launch_bounds__(256) void dt_fix(const u16* __restrict__ BCm,
                                              const float* __restrict__ dt_bias,
                                              const float* __restrict__ A_log,
                                              float* __restrict__ dtv,
                                              float* __restrict__ decayv) {
    int i = blockIdx.x * 256 + threadIdx.x;   // grid 256 -> 65536 = ROWS*NHEAD
    int row = i >> 4, h = i & 15;
    float z = bf2f(BCm[(size_t)row * BCSTR + 2048 + h]) + dt_bias[h];
    float sp = (z > 20.f) ? z : log1pf(expf(z));
    dtv[i] = sp;
    decayv[i] = expf(-expf(A_log[h]) * sp);
}

// ---------------- seg_state: segment-final states as weighted outer-product sum ----------------
__global__ __launch_bounds__(256) void seg_state(const u16* __restrict__ xw,
                                                 const u16* __restrict__ BCm,
                                                 const float* __restrict__ dtv,
                                                 const float* __restrict__ decayv,
                                                 float* __restrict__ Hbuf) {
    const int blk = blockIdx.x;
    const int seg = blk >> 7;
    const int b   = (blk >> 4) & 7;
    const int h   = blk & 15;
    const int tid = threadIdx.x;
    const int pgrp = tid >> 3;
    const int oct  = tid & 7;

    __shared__ __align__(16) u16 sx[SEGT][PDIM];
    __shared__ __align__(16) u16 sbm[SEGT][NSTATE];
    __shared__ float sw[SEGT];
    __shared__ float sdt[SEGT];
    __shared__ float sdec[SEGT];
    __shared__ float sP[32];

    const int t0 = seg * SEGT;

#pragma unroll
    for (int k = 0; k < 8; ++k) {
        int idx = tid + k * 256;
        int t = idx >> 4, c = (idx & 15) * 8;
        int r = (t0 + t) * B_SZ + b;
        *(uint4*)&sx[t][c] = *(const uint4*)(xw + (size_t)r * D_IN + h * PDIM + c);
    }
#pragma unroll
    for (int k = 0; k < 4; ++k) {
        int idx = tid + k * 256;
        int t = idx >> 3, c = (idx & 7) * 8;
        int r = (t0 + t) * B_SZ + b;
        *(uint4*)&sbm[t][c] = *(const uint4*)(BCm + (size_t)r * BCSTR + h * NSTATE + c);
    }
    if (tid < SEGT)            sdt[tid] = dtv[((t0 + tid) * B_SZ + b) * NHEAD + h];
    else if (tid < 2 * SEGT)   sdec[tid - SEGT] = decayv[((t0 + tid - SEGT) * B_SZ + b) * NHEAD + h];
    __syncthreads();

    if (tid < 32) {
        float p = 1.f;
        for (int i = 3; i >= 0; --i) {
            int t = tid * 4 + i;
            sw[t] = sdt[t] * p;
            p *= sdec[t];
        }
        sP[tid] = p;
    }
    __syncthreads();
    if (tid == 0) {
        float suf = 1.f;
        for (int q = 31; q >= 0; --q) { float tmp = sP[q]; sP[q] = suf; suf *= tmp; }
    }
    __syncthreads();
    if (tid < 32) {
        float m = sP[tid];
        for (int i = 0; i < 4; ++i) sw[tid * 4 + i] *= m;
    }
    __syncthreads();

    float acc[4][8];
#pragma unroll
    for (int i = 0; i < 4; i++)
#pragma unroll
        for (int j = 0; j < 8; j++) acc[i][j] = 0.f;

    for (int t = 0; t < SEGT; ++t) {
        float w = sw[t];
        const u16* xp = &sx[t][pgrp * 4];
        const u16* bp = &sbm[t][oct * 8];
        float xv[4], bv[8];
#pragma unroll
        for (int i = 0; i < 4; i++) xv[i] = w * bf2f(xp[i]);
#pragma unroll
        for (int j = 0; j < 8; j++) bv[j] = bf2f(bp[j]);
#pragma unroll
        for (int i = 0; i < 4; i++)
#pragma unroll
            for (int j = 0; j < 8; j++)
                acc[i][j] = fmaf(xv[i], bv[j], acc[i][j]);
    }

    float* base = Hbuf + (size_t)seg * SLOT +
                  (((size_t)b * NHEAD + h) * PDIM + pgrp * 4) * NSTATE + oct * 8;
#pragma unroll
    for (int i = 0; i < 4; i++) {
        *(float4*)(base + (size_t)i * NSTATE)     = make_float4(acc[i][0], acc[i][1], acc[i][2], acc[i][3]);
        *(float4*)(base + (size_t)i * NSTATE + 4) = make_float4(acc[i][4], acc[i][5], acc[i][6], acc[i][7]);
    }
}

// ---------------- prefix combine -> bf16 prefix states Hbf ----------------
__global__ __launch_bounds__(256) void seg_prefix(const float* __restrict__ Hbuf,
                                                  const float* __restrict__ decayv,
                                                  u16* __restrict__ Hbf) {
    const int blk = blockIdx.x;
    const int b  = blk >> 6;
    const int h  = (blk >> 2) & 15;
    const int ec = blk & 3;
    const int tid = threadIdx.x;

    __shared__ float sA[NSEG];

    if (tid < 64 * (NSEG - 2)) {
        int s = 1 + (tid >> 6);
        int i = tid & 63;
        int t = s * SEGT + i * 2;
        float p = decayv[(t * B_SZ + b) * NHEAD + h] *
                  decayv[((t + 1) * B_SZ + b) * NHEAD + h];
        p *= __shfl_xor(p, 1);
        p *= __shfl_xor(p, 2);
        p *= __shfl_xor(p, 4);
        p *= __shfl_xor(p, 8);
        p *= __shfl_xor(p, 16);
        p *= __shfl_xor(p, 32);
        if (i == 0) sA[s] = p;
    }
    __syncthreads();

    const size_t base = (((size_t)b * NHEAD + h) * PDIM * NSTATE) + (size_t)ec * 2048 + tid * 8;
    float4 P0 = *(const float4*)(Hbuf + base);
    float4 P1 = *(const float4*)(Hbuf + base + 4);
    u16 pk[8];
    pk[0] = f2bf(P0.x); pk[1] = f2bf(P0.y); pk[2] = f2bf(P0.z); pk[3] = f2bf(P0.w);
    pk[4] = f2bf(P1.x); pk[5] = f2bf(P1.y); pk[6] = f2bf(P1.z); pk[7] = f2bf(P1.w);
    *(uint4*)(Hbf + base) = *(const uint4*)pk;
#pragma unroll
    for (int s = 1; s <= NSEG - 2; ++s) {
        float a = sA[s];
        const float* slot = Hbuf + (size_t)s * SLOT + base;
        float4 h0 = *(const float4*)(slot);
        float4 h1 = *(const float4*)(slot + 4);
        P0.x = fmaf(a, P0.x, h0.x); P0.y = fmaf(a, P0.y, h0.y);
        P0.z = fmaf(a, P0.z, h0.z); P0.w = fmaf(a, P0.w, h0.w);
        P1.x = fmaf(a, P1.x, h1.x); P1.y = fmaf(a, P1.y, h1.y);
        P1.z = fmaf(a, P1.z, h1.z); P1.w = fmaf(a, P1.w, h1.w);
        pk[0] = f2bf(P0.x); pk[1] = f2bf(P0.y); pk[2] = f2bf(P0.z); pk[3] = f2bf(P0.w);
        pk[4] = f2bf(P1.x); pk[5] = f2bf(P1.y); pk[6] = f2bf(P1.z); pk[7] = f2bf(P1.w);
        *(uint4*)(Hbf + (size_t)s * SLOT + base) = *(const uint4*)pk;
    }
}

// ---------------- chunk_scan: fused S' build + Y = exp(L).C@Hp^T + S'@X^T ----------------
__global__ __launch_bounds__(256) void chunk_scan(const u16* __restrict__ BCm,
                                                  const float* __restrict__ dtv,
                                                  const float* __restrict__ decayv,
                                                  const u16* __restrict__ Hbf,
                                                  u16* __restrict__ xb) {
    __shared__ __align__(16) u16 sB_[128][68];   // B [t'][n]
    __shared__ __align__(16) u16 sC_[128][68];   // C [t][n]
    __shared__ __align__(16) u16 sS[128][132];   // S' [t][t']
    __shared__ __align__(16) u16 sXT[128][36];   // X^T [p][k-tile]
    __shared__ float sdt[SEGT], sL[SEGT], sEL[SEGT], stmp[32];

    const int blk = blockIdx.x;
    const int seg = blk >> 7, b = (blk >> 4) & 7, h = blk & 15;
    const int tid = threadIdx.x;
    const int wave = tid >> 6, lane = tid & 63;
    const int quad = lane >> 4, lr = lane & 15;
    const int wm = wave & 1, wn = wave >> 1;
    const int t0 = seg * SEGT;

#pragma unroll
    for (int it = 0; it < 4; ++it) {
        int idx = tid + it * 256;
        int t = idx >> 3, c = (idx & 7) * 8;
        int r = (t0 + t) * B_SZ + b;
        *(uint4*)&sB_[t][c] = *(const uint4*)(BCm + (size_t)r * BCSTR + h * NSTATE + c);
        *(uint4*)&sC_[t][c] = *(const uint4*)(BCm + (size_t)r * BCSTR + 1024 + h * NSTATE + c);
    }
    if (tid < SEGT) sdt[tid] = dtv[((t0 + tid) * B_SZ + b) * NHEAD + h];
    else if (tid < 2 * SEGT) {
        int t = tid - SEGT;
        sL[t] = __logf(fmaxf(decayv[((t0 + t) * B_SZ + b) * NHEAD + h], 1e-30f));
    }
    __syncthreads();
    if (tid < 32) {
        float s = 0.f, v[4];
#pragma unroll
        for (int i = 0; i < 4; ++i) { s += sL[tid * 4 + i]; v[i] = s; }
        stmp[tid] = s;
#pragma unroll
        for (int i = 0; i < 4; ++i) sL[tid * 4 + i] = v[i];
    }
    __syncthreads();
    if (tid == 0) {
        float run = 0.f;
        for (int q = 0; q < 32; ++q) { float c2 = stmp[q]; stmp[q] = run; run += c2; }
    }
    __syncthreads();
    if (tid < 32) {
        float off = stmp[tid];
#pragma unroll
        for (int i = 0; i < 4; ++i) sL[tid * 4 + i] += off;
    }
    __syncthreads();
    if (tid < SEGT) sEL[tid] = __expf(sL[tid]);

    floatx4 accS[4][4];
#pragma unroll
    for (int i = 0; i < 4; i++)
#pragma unroll
        for (int j = 0; j < 4; j++)
#pragma unroll
            for (int r = 0; r < 4; r++) accS[i][j][r] = 0.f;
#pragma unroll
    for (int k0 = 0; k0 < 64; k0 += 32) {
        bf16x8 af[4], bfr[4];
#pragma unroll
        for (int i = 0; i < 4; i++)
            af[i] = *(const bf16x8*)&sB_[wm * 64 + i * 16 + lr][k0 + quad * 8];
#pragma unroll
        for (int j = 0; j < 4; j++)
            bfr[j] = *(const bf16x8*)&sC_[wn * 64 + j * 16 + lr][k0 + quad * 8];
#pragma unroll
        for (int i = 0; i < 4; i++)
#pragma unroll
            for (int j = 0; j < 4; j++)
                accS[i][j] = __builtin_amdgcn_mfma_f32_16x16x32_bf16(af[i], bfr[j], accS[i][j], 0, 0, 0);
    }
#pragma unroll
    for (int j = 0; j < 4; j++) {
        int tt = wn * 64 + j * 16 + lr;
        float Lt = sL[tt];
#pragma unroll
        for (int i = 0; i < 4; i++) {
#pragma unroll
            for (int r = 0; r < 4; r++) {
                int tp = wm * 64 + i * 16 + quad * 4 + r;
                float v = 0.f;
                if (tp <= tt) v = accS[i][j][r] * sdt[tp] * __expf(Lt - sL[tp]);
                sS[tt][tp] = f2bf(v);
            }
        }
    }

    floatx4 acc[4][4];
#pragma unroll
    for (int i = 0; i < 4; i++)
#pragma unroll
        for (int j = 0; j < 4; j++)
#pragma unroll
            for (int r = 0; r < 4; r++) acc[i][j][r] = 0.f;
    __syncthreads();
    if (seg > 0) {
        const u16* hbase = Hbf + (size_t)(seg - 1) * SLOT + (((size_t)b * NHEAD + h) * PDIM) * NSTATE;
#pragma unroll
        for (int k0 = 0; k0 < 64; k0 += 32) {
            bf16x8 af[4], bfr[4];
#pragma unroll
            for (int i = 0; i < 4; i++)
                af[i] = *(const bf16x8*)&sC_[wm * 64 + i * 16 + lr][k0 + quad * 8];
#pragma unroll
            for (int j = 0; j < 4; j++)
                bfr[j] = *(const bf16x8*)(hbase + (size_t)(wn * 64 + j * 16 + lr) * NSTATE + k0 + quad * 8);
#pragma unroll
            for (int i = 0; i < 4; i++)
#pragma unroll
                for (int j = 0; j < 4; j++)
                    acc[i][j] = __builtin_amdgcn_mfma_f32_16x16x32_bf16(af[i], bfr[j], acc[i][j], 0, 0, 0);
        }
#pragma unroll
        for (int i = 0; i < 4; i++) {
#pragma unroll
            for (int r = 0; r < 4; r++) {
                float el = sEL[wm * 64 + i * 16 + quad * 4 + r];
#pragma unroll
                for (int j = 0; j < 4; j++) acc[i][j][r] *= el;
            }
        }
    }

    const int px = tid & 127, koh = (tid >> 7) * 16;
    for (int kc = 0; kc < 128; kc += 32) {
        u16 xv[16];
#pragma unroll
        for (int j2 = 0; j2 < 16; ++j2) {
            int tp = kc + koh + j2;
            xv[j2] = xb[(size_t)((t0 + tp) * B_SZ + b) * D_IN + h * PDIM + px];
        }
        __syncthreads();
        *(uint4*)&sXT[px][koh]     = *(const uint4*)&xv[0];
        *(uint4*)&sXT[px][koh + 8] = *(const uint4*)&xv[8];
        __syncthreads();
        bf16x8 af[4], bfr[4];
#pragma unroll
        for (int i = 0; i < 4; i++)
            af[i] = *(const bf16x8*)&sS[wm * 64 + i * 16 + lr][kc + quad * 8];
#pragma unroll
        for (int j = 0; j < 4; j++)
            bfr[j] = *(const bf16x8*)&sXT[wn * 64 + j * 16 + lr][quad * 8];
#pragma unroll
        for (int i = 0; i < 4; i++)
#pragma unroll
            for (int j = 0; j < 4; j++)
                acc[i][j] = __builtin_amdgcn_mfma_f32_16x16x32_bf16(af[i], bfr[j], acc[i][j], 0, 0, 0);
    }

#pragma unroll
    for (int j = 0; j < 4; j++) {
        int p = wn * 64 + j * 16 + lr;
#pragma unroll
        for (int i = 0; i < 4; i++) {
#pragma unroll
            for (int r = 0; r < 4; r++) {
                int t = wm * 64 + i * 16 + quad * 4 + r;
                xb[(size_t)((t0 + t) * B_SZ + b) * D_IN + h * PDIM + p] = f2bf(acc[i][j][r]);
            }
        }
    }
}

// ---------------- launch ----------------
extern "C" void kernel_launch(void* const* d_in, const int* in_sizes, int n_in,
                              void* d_out, int out_size, void* d_ws, size_t ws_size,
                              hipStream_t stream) {
    const float* obs     = (const float*)d_in[0];
    const float* W_in    = (const float*)d_in[1];
    const float* b_in    = (const float*)d_in[2];
    const float* A_log   = (const float*)d_in[3];
    const float* dt_bias = (const float*)d_in[4];
    const float* W_dt    = (const float*)d_in[5];
    const float* W_B     = (const float*)d_in[6];
    const float* W_C     = (const float*)d_in[7];
    const float* W_yo    = (const float*)d_in[8];
    const float* b_yo    = (const float*)d_in[9];
    const float* W_head  = (const float*)d_in[10];
    const float* b_head  = (const float*)d_in[11];

    char* ws = (char*)d_ws;
    size_t o = 0;
    u16*   xb     = (u16*)(ws + o);   o += (size_t)ROWS * D_IN * 2;            // 16 MB (x, then y in-place)
    u16*   BCm    = (u16*)(ws + o);   o += (size_t)ROWS * BCSTR * 2;           // 17.8 MB (B | C | dtraw | pad)
    float* dtv    = (float*)(ws + o); o += (size_t)ROWS * NHEAD * 4;
    float* decayv = (float*)(ws + o); o += (size_t)ROWS * NHEAD * 4;
    u16*   zb     = (u16*)(ws + o);   o += (size_t)ROWS * NUNITS * 2;          // 2 MB
    float* Hseg   = (float*)(ws + o); o += (size_t)(NSEG - 1) * SLOT * 4;      // 12 MB
    u16*   Hbf    = (u16*)(ws + o);   o += (size_t)(NSEG - 1) * SLOT * 2;      // 6 MB
    u16*   obsb   = (u16*)(ws + o);   o += (size_t)ROWS * OBS_D * 2;           // 2 MB
    u16*   WinT   = (u16*)(ws + o);   o += (size_t)D_IN * OBS_D * 2;           // 1 MB
    u16*   WBCT   = (u16*)(ws + o);   o += (size_t)BCSTR * D_IN * 2;           // 8.9 MB
    u16*   WyoT   = (u16*)(ws + o);   o += (size_t)NUNITS * D_IN * 2;          // 1 MB
    u16*   WheadT = (u16*)(ws + o);   o += (size_t)NACT * NUNITS * 2;

    // zero-work launch of the harness-required symbol (kept referenced)
    ActorAgent_27625229647898_kernel<<<dim3(1), 256, 0, stream>>>((float*)d_out, 0, 0.f);

    // ---- all weight prep in one launch ----
    prep<<<dim3(160 + 5136), 256, 0, stream>>>(obs, W_dt, W_in, W_B, W_C, W_yo, W_head,
                                               obsb, WinT, WBCT, WyoT, WheadT);

    // ---- x = relu(obs @ W_in + b_in) -> bf16 ----
    gemm_bt128<1, 1, 1><<<dim3(32, 16), 256, 0, stream>>>(obsb, WinT, b_in, xb, ROWS, D_IN, OBS_D);
    // ---- B|C|dtraw projection (N = 2176, exactly 17 tiles) ----
    gemm_bt128<0, 1, 0><<<dim3(32, 17), 256, 0, stream>>>(xb, WBCT, (const float*)nullptr, BCm, ROWS, BCSTR, D_IN);
    // ---- dt = softplus(dtraw + dt_bias); decay = exp(-exp(A_log)*dt) ----
    dt_fix<<<dim3(256), 256, 0, stream>>>(BCm, dt_bias, A_log, dtv, decayv);
    // ---- scan: A) segment-local final states ----
    seg_state<<<dim3((NSEG - 1) * 128), 256, 0, stream>>>(xb, BCm, dtv, decayv, Hseg);
    //          B) prefix combine -> bf16 ----
    seg_prefix<<<dim3(512), 256, 0, stream>>>(Hseg, decayv, Hbf);
    //          C) fused S' + Y, in-place over xb ----
    chunk_scan<<<dim3(NSEG * 128), 256, 0, stream>>>(BCm, dtv, decayv, Hbf, xb);
    // ---- z = relu(y @ W_yo + b_yo) -> bf16 ----
    gemm_bt64<1, 1><<<dim3(64, 4), 256, 0, stream>>>(xb, WyoT, b_yo, zb, ROWS, NUNITS, D_IN);
    // ---- logits = z @ W_head + b_head -> d_out (fp32) ----
    gemm_bt64<0, 0><<<dim3(64, 1), 256, 0, stream>>>(zb, WheadT, b_head, (float*)d_out, ROWS, NACT, NUNITS);
}

// Round 18
// 248.912 us; speedup vs baseline: 1.0298x; 1.0298x over previous
//
#include <hip/hip_runtime.h>
#include <cstdint>
#include <cstddef>

typedef unsigned short u16;
typedef __attribute__((ext_vector_type(8))) __bf16 bf16x8;   // MFMA A/B operand
typedef __attribute__((ext_vector_type(4))) float floatx4;   // MFMA C/D operand

// dims
#define T_DIM   512
#define B_SZ    8
#define ROWS    4096      // T*B
#define OBS_D   256
#define D_IN    2048
#define NHEAD   16
#define NSTATE  64
#define PDIM    128
#define NUNITS  256
#define NACT    64
#define NSEG    4
#define SEGT    128       // T_DIM / NSEG
#define SLOT    (B_SZ * NHEAD * PDIM * NSTATE)   // 1048576 elems per seg-state slot
#define BCSTR   2176      // BCm row stride: B(1024) | C(1024) | dtraw(16) | pad(112) = 17 x 128

__host__ __device__ __forceinline__ float bf2f(u16 u) {
    union { uint32_t i; float f; } v; v.i = ((uint32_t)u) << 16; return v.f;
}
__host__ __device__ __forceinline__ u16 f2bf(float f) {
    union { float f; uint32_t i; } v; v.f = f;
    uint32_t r = v.i + 0x7FFFu + ((v.i >> 16) & 1u);
    return (u16)(r >> 16);
}

// async 16B/lane global->LDS (m97 pattern). lds ptr must be wave-uniform.
__device__ __forceinline__ void glds16(const u16* g, u16* l) {
    __builtin_amdgcn_global_load_lds(
        (__attribute__((address_space(1))) void*)g,
        (__attribute__((address_space(3))) void*)l, 16, 0, 0);
}

// ---------------- harness-required symbol (zero-work launch keeps it referenced) ----------------
__global__ __launch_bounds__(256) void ActorAgent_27625229647898_kernel(
        float* __restrict__ out, int n, float v) {
    for (int i = blockIdx.x * 256 + threadIdx.x; i < n; i += gridDim.x * 256)
        out[i] = v;
}

// ---------------- prep: all weight converts + transposes in ONE launch ----------------
// flat section: obs cvt, W_dt^T scatter into WBCT rows 2048..2063, zero rows 2064..2175.
__global__ __launch_bounds__(256) void prep(const float* __restrict__ obs,
                                            const float* __restrict__ W_dt,
                                            const float* __restrict__ W_in,
                                            const float* __restrict__ W_B,
                                            const float* __restrict__ W_C,
                                            const float* __restrict__ W_yo,
                                            const float* __restrict__ W_head,
                                            u16* __restrict__ obsb,
                                            u16* __restrict__ WinT, u16* __restrict__ WBCT,
                                            u16* __restrict__ WyoT, u16* __restrict__ WheadT) {
    int bid = blockIdx.x;
    if (bid < 160) {
        const int NOBS = ROWS * OBS_D;             // 1048576
        const int NDT  = D_IN * NHEAD;             // 32768
        const int NZ   = 112 * D_IN;               // 229376 (zero pad rows 2064..2175)
        for (int i = bid * 256 + threadIdx.x; i < NOBS + NDT + NZ; i += 160 * 256) {
            if (i < NOBS) obsb[i] = f2bf(obs[i]);
            else if (i < NOBS + NDT) {
                int j = i - NOBS;                  // j = k*16 + n
                int k = j >> 4, n = j & 15;
                WBCT[(size_t)(2048 + n) * D_IN + k] = f2bf(W_dt[j]);
            } else {
                WBCT[(size_t)2064 * D_IN + (i - NOBS - NDT)] = 0;
            }
        }
        return;
    }
    bid -= 160;
    const float* src; u16* dst; int R, C, bx, by;
    if (bid < 512)       { src = W_in;   dst = WinT;   R = 256;  C = 2048; bx = bid & 63; by = bid >> 6; }
    else if (bid < 2560) { int i = bid - 512;  src = W_B;  dst = WBCT; R = 2048; C = 1024; bx = i & 31; by = i >> 5; }
    else if (bid < 4608) { int i = bid - 2560; src = W_C;  dst = WBCT + (size_t)1024 * 2048; R = 2048; C = 1024; bx = i & 31; by = i >> 5; }
    else if (bid < 5120) { int i = bid - 4608; src = W_yo; dst = WyoT; R = 2048; C = 256;  bx = i & 7;  by = i >> 3; }
    else                 { int i = bid - 5120; src = W_head; dst = WheadT; R = 256; C = 64; bx = i & 1; by = i >> 1; }
    __shared__ float t[32][33];
    int c0 = bx * 32, r0 = by * 32;
    int tx = threadIdx.x & 31, ty = threadIdx.x >> 5;
#pragma unroll
    for (int i = 0; i < 32; i += 8)
        t[ty + i][tx] = src[(size_t)(r0 + ty + i) * C + c0 + tx];
    __syncthreads();
#pragma unroll
    for (int i = 0; i < 32; i += 8)
        dst[(size_t)(c0 + ty + i) * R + r0 + tx] = f2bf(t[tx][ty + i]);
}

// ---------------- bt128: 128x128 bf16 MFMA GEMM, B^T (N,K), BK=32 glds staging ----------------
// Proven round-13 structure: unpadded [row][32] LDS, 4 glds16/thread-group/iter,
// 16 MFMA per wave-iter, 2 barriers/iter. Best measured variant.
// NOTE (r14/r15/r17 post-mortems): BK=64 (bank conflicts 3x), 128x64 tile
// (MFMA/barrier halved), and XCD swizzle (A thrashes per-XCD L2) all regress.
template <int ACT, int OUT_BF16, int HAS_BIAS>
__global__ __launch_bounds__(256) void gemm_bt128(const u16* __restrict__ A,
                                                  const u16* __restrict__ BT,
                                                  const float* __restrict__ bias,
                                                  void* __restrict__ Cout,
                                                  int M, int N, int K) {
    __shared__ __align__(16) u16 sA[128 * 32];
    __shared__ __align__(16) u16 sB[128 * 32];
    const int tid  = threadIdx.x;
    const int wave = tid >> 6, lane = tid & 63;
    const int quad = lane >> 4, lr = lane & 15;
    const int wm = wave & 1, wn = wave >> 1;
    const int m0 = blockIdx.x * 128, n0 = blockIdx.y * 128;
    const int r0 = wave * 32 + (lane >> 2);   // staged row per lane
    const int kel = (lane & 3) * 8;           // k offset (u16) per lane

    floatx4 acc[4][4];
#pragma unroll
    for (int i = 0; i < 4; i++)
#pragma unroll
        for (int j = 0; j < 4; j++)
#pragma unroll
            for (int r = 0; r < 4; r++) acc[i][j][r] = 0.f;

    const u16* apg = A + (size_t)(m0 + r0) * K + kel;
    const u16* bpg = BT + (size_t)(n0 + r0) * K + kel;
    u16* lA0 = &sA[(wave * 32) * 32];
    u16* lA1 = &sA[(wave * 32 + 16) * 32];
    u16* lB0 = &sB[(wave * 32) * 32];
    u16* lB1 = &sB[(wave * 32 + 16) * 32];

    for (int k0 = 0; k0 < K; k0 += 32) {
        __syncthreads();   // previous iteration's LDS readers done
        glds16(apg + k0, lA0);
        glds16(apg + (size_t)16 * K + k0, lA1);
        glds16(bpg + k0, lB0);
        glds16(bpg + (size_t)16 * K + k0, lB1);
        __syncthreads();   // drain vmcnt -> LDS visible
        bf16x8 af[4], bfr[4];
#pragma unroll
        for (int i = 0; i < 4; i++)
            af[i] = *(const bf16x8*)&sA[(wm * 64 + i * 16 + lr) * 32 + quad * 8];
#pragma unroll
        for (int j = 0; j < 4; j++)
            bfr[j] = *(const bf16x8*)&sB[(wn * 64 + j * 16 + lr) * 32 + quad * 8];
#pragma unroll
        for (int i = 0; i < 4; i++)
#pragma unroll
            for (int j = 0; j < 4; j++)
                acc[i][j] = __builtin_amdgcn_mfma_f32_16x16x32_bf16(af[i], bfr[j], acc[i][j], 0, 0, 0);
    }
    // C/D layout: col = lane&15, row = quad*4 + reg
#pragma unroll
    for (int j = 0; j < 4; j++) {
        int col = n0 + wn * 64 + j * 16 + lr;
        float bvv = HAS_BIAS ? bias[col] : 0.f;
#pragma unroll
        for (int i = 0; i < 4; i++) {
#pragma unroll
            for (int r = 0; r < 4; r++) {
                int row = m0 + wm * 64 + i * 16 + quad * 4 + r;
                float v = acc[i][j][r] + bvv;
                if (ACT) v = fmaxf(v, 0.f);
                if (OUT_BF16) ((u16*)Cout)[(size_t)row * N + col] = f2bf(v);
                else          ((float*)Cout)[(size_t)row * N + col] = v;
            }
        }
    }
}

// ---------------- bt64: 64x64 bf16 MFMA GEMM, B^T layout, BK=64 glds staging ----------------
template <int ACT, int OUT_BF16>
__global__ __launch_bounds__(256) void gemm_bt64(const u16* __restrict__ A,
                                                 const u16* __restrict__ BT,
                                                 const float* __restrict__ bias,
                                                 void* __restrict__ Cout,
                                                 int M, int N, int K) {
    __shared__ __align__(16) u16 sA[64 * 64];  // 8 KB
    __shared__ __align__(16) u16 sB[64 * 64];
    const int tid  = threadIdx.x;
    const int wave = tid >> 6, lane = tid & 63;
    const int quad = lane >> 4, lr = lane & 15;
    const int m0 = blockIdx.x * 64, n0 = blockIdx.y * 64;
    const int srl = lane >> 3, sc = (lane & 7) * 8;

    floatx4 acc[4];
#pragma unroll
    for (int i = 0; i < 4; i++)
#pragma unroll
        for (int j = 0; j < 4; j++) acc[i][j] = 0.f;

    const u16* apg = A + (size_t)(m0 + wave * 16 + srl) * K + sc;
    const u16* bpg = BT + (size_t)(n0 + wave * 16 + srl) * K + sc;

    for (int k0 = 0; k0 < K; k0 += 64) {
        __syncthreads();
#pragma unroll
        for (int g = 0; g < 2; ++g) {
            glds16(apg + (size_t)(g * 8) * K + k0, &sA[(wave * 16 + g * 8) * 64]);
            glds16(bpg + (size_t)(g * 8) * K + k0, &sB[(wave * 16 + g * 8) * 64]);
        }
        __syncthreads();
#pragma unroll
        for (int ks = 0; ks < 2; ++ks) {
            bf16x8 af = *(const bf16x8*)&sA[(wave * 16 + lr) * 64 + ks * 32 + quad * 8];
#pragma unroll
            for (int nt = 0; nt < 4; nt++) {
                bf16x8 bf = *(const bf16x8*)&sB[(nt * 16 + lr) * 64 + ks * 32 + quad * 8];
                acc[nt] = __builtin_amdgcn_mfma_f32_16x16x32_bf16(af, bf, acc[nt], 0, 0, 0);
            }
        }
    }
#pragma unroll
    for (int nt = 0; nt < 4; nt++) {
        int col = n0 + nt * 16 + lr;
        float bvv = bias ? bias[col] : 0.f;
#pragma unroll
        for (int r = 0; r < 4; r++) {
            int row = m0 + wave * 16 + quad * 4 + r;
            float v = acc[nt][r] + bvv;
            if (ACT) v = fmaxf(v, 0.f);
            if (OUT_BF16) ((u16*)Cout)[(size_t)row * N + col] = f2bf(v);
            else          ((float*)Cout)[(size_t)row * N + col] = v;
        }
    }
}

// ---------------- dt_fix: softplus + decay from GEMM-produced dtraw ----------------
__global__ __launch_bounds__(256) void dt_fix(const u16* __restrict__ BCm,
                                              const float* __restrict__ dt_bias,
                                              const float* __restrict__ A_log,
                                              float* __restrict__ dtv,
                                              float* __restrict__ decayv) {
    int i = blockIdx.x * 256 + threadIdx.x;   // grid 256 -> 65536 = ROWS*NHEAD
    int row = i >> 4, h = i & 15;
    float z = bf2f(BCm[(size_t)row * BCSTR + 2048 + h]) + dt_bias[h];
    float sp = (z > 20.f) ? z : log1pf(expf(z));
    dtv[i] = sp;
    decayv[i] = expf(-expf(A_log[h]) * sp);
}

// ---------------- seg_state: segment-final states as weighted outer-product sum ----------------
__global__ __launch_bounds__(256) void seg_state(const u16* __restrict__ xw,
                                                 const u16* __restrict__ BCm,
                                                 const float* __restrict__ dtv,
                                                 const float* __restrict__ decayv,
                                                 float* __restrict__ Hbuf) {
    const int blk = blockIdx.x;
    const int seg = blk >> 7;
    const int b   = (blk >> 4) & 7;
    const int h   = blk & 15;
    const int tid = threadIdx.x;
    const int pgrp = tid >> 3;
    const int oct  = tid & 7;

    __shared__ __align__(16) u16 sx[SEGT][PDIM];
    __shared__ __align__(16) u16 sbm[SEGT][NSTATE];
    __shared__ float sw[SEGT];
    __shared__ float sdt[SEGT];
    __shared__ float sdec[SEGT];
    __shared__ float sP[32];

    const int t0 = seg * SEGT;

#pragma unroll
    for (int k = 0; k < 8; ++k) {
        int idx = tid + k * 256;
        int t = idx >> 4, c = (idx & 15) * 8;
        int r = (t0 + t) * B_SZ + b;
        *(uint4*)&sx[t][c] = *(const uint4*)(xw + (size_t)r * D_IN + h * PDIM + c);
    }
#pragma unroll
    for (int k = 0; k < 4; ++k) {
        int idx = tid + k * 256;
        int t = idx >> 3, c = (idx & 7) * 8;
        int r = (t0 + t) * B_SZ + b;
        *(uint4*)&sbm[t][c] = *(const uint4*)(BCm + (size_t)r * BCSTR + h * NSTATE + c);
    }
    if (tid < SEGT)            sdt[tid] = dtv[((t0 + tid) * B_SZ + b) * NHEAD + h];
    else if (tid < 2 * SEGT)   sdec[tid - SEGT] = decayv[((t0 + tid - SEGT) * B_SZ + b) * NHEAD + h];
    __syncthreads();

    if (tid < 32) {
        float p = 1.f;
        for (int i = 3; i >= 0; --i) {
            int t = tid * 4 + i;
            sw[t] = sdt[t] * p;
            p *= sdec[t];
        }
        sP[tid] = p;
    }
    __syncthreads();
    if (tid == 0) {
        float suf = 1.f;
        for (int q = 31; q >= 0; --q) { float tmp = sP[q]; sP[q] = suf; suf *= tmp; }
    }
    __syncthreads();
    if (tid < 32) {
        float m = sP[tid];
        for (int i = 0; i < 4; ++i) sw[tid * 4 + i] *= m;
    }
    __syncthreads();

    float acc[4][8];
#pragma unroll
    for (int i = 0; i < 4; i++)
#pragma unroll
        for (int j = 0; j < 8; j++) acc[i][j] = 0.f;

    for (int t = 0; t < SEGT; ++t) {
        float w = sw[t];
        const u16* xp = &sx[t][pgrp * 4];
        const u16* bp = &sbm[t][oct * 8];
        float xv[4], bv[8];
#pragma unroll
        for (int i = 0; i < 4; i++) xv[i] = w * bf2f(xp[i]);
#pragma unroll
        for (int j = 0; j < 8; j++) bv[j] = bf2f(bp[j]);
#pragma unroll
        for (int i = 0; i < 4; i++)
#pragma unroll
            for (int j = 0; j < 8; j++)
                acc[i][j] = fmaf(xv[i], bv[j], acc[i][j]);
    }

    float* base = Hbuf + (size_t)seg * SLOT +
                  (((size_t)b * NHEAD + h) * PDIM + pgrp * 4) * NSTATE + oct * 8;
#pragma unroll
    for (int i = 0; i < 4; i++) {
        *(float4*)(base + (size_t)i * NSTATE)     = make_float4(acc[i][0], acc[i][1], acc[i][2], acc[i][3]);
        *(float4*)(base + (size_t)i * NSTATE + 4) = make_float4(acc[i][4], acc[i][5], acc[i][6], acc[i][7]);
    }
}

// ---------------- prefix combine -> bf16 prefix states Hbf ----------------
__global__ __launch_bounds__(256) void seg_prefix(const float* __restrict__ Hbuf,
                                                  const float* __restrict__ decayv,
                                                  u16* __restrict__ Hbf) {
    const int blk = blockIdx.x;
    const int b  = blk >> 6;
    const int h  = (blk >> 2) & 15;
    const int ec = blk & 3;
    const int tid = threadIdx.x;

    __shared__ float sA[NSEG];

    if (tid < 64 * (NSEG - 2)) {
        int s = 1 + (tid >> 6);
        int i = tid & 63;
        int t = s * SEGT + i * 2;
        float p = decayv[(t * B_SZ + b) * NHEAD + h] *
                  decayv[((t + 1) * B_SZ + b) * NHEAD + h];
        p *= __shfl_xor(p, 1);
        p *= __shfl_xor(p, 2);
        p *= __shfl_xor(p, 4);
        p *= __shfl_xor(p, 8);
        p *= __shfl_xor(p, 16);
        p *= __shfl_xor(p, 32);
        if (i == 0) sA[s] = p;
    }
    __syncthreads();

    const size_t base = (((size_t)b * NHEAD + h) * PDIM * NSTATE) + (size_t)ec * 2048 + tid * 8;
    float4 P0 = *(const float4*)(Hbuf + base);
    float4 P1 = *(const float4*)(Hbuf + base + 4);
    u16 pk[8];
    pk[0] = f2bf(P0.x); pk[1] = f2bf(P0.y); pk[2] = f2bf(P0.z); pk[3] = f2bf(P0.w);
    pk[4] = f2bf(P1.x); pk[5] = f2bf(P1.y); pk[6] = f2bf(P1.z); pk[7] = f2bf(P1.w);
    *(uint4*)(Hbf + base) = *(const uint4*)pk;
#pragma unroll
    for (int s = 1; s <= NSEG - 2; ++s) {
        float a = sA[s];
        const float* slot = Hbuf + (size_t)s * SLOT + base;
        float4 h0 = *(const float4*)(slot);
        float4 h1 = *(const float4*)(slot + 4);
        P0.x = fmaf(a, P0.x, h0.x); P0.y = fmaf(a, P0.y, h0.y);
        P0.z = fmaf(a, P0.z, h0.z); P0.w = fmaf(a, P0.w, h0.w);
        P1.x = fmaf(a, P1.x, h1.x); P1.y = fmaf(a, P1.y, h1.y);
        P1.z = fmaf(a, P1.z, h1.z); P1.w = fmaf(a, P1.w, h1.w);
        pk[0] = f2bf(P0.x); pk[1] = f2bf(P0.y); pk[2] = f2bf(P0.z); pk[3] = f2bf(P0.w);
        pk[4] = f2bf(P1.x); pk[5] = f2bf(P1.y); pk[6] = f2bf(P1.z); pk[7] = f2bf(P1.w);
        *(uint4*)(Hbf + (size_t)s * SLOT + base) = *(const uint4*)pk;
    }
}

// ---------------- chunk_scan: fused S' build + Y = exp(L).C@Hp^T + S'@X^T ----------------
__global__ __launch_bounds__(256) void chunk_scan(const u16* __restrict__ BCm,
                                                  const float* __restrict__ dtv,
                                                  const float* __restrict__ decayv,
                                                  const u16* __restrict__ Hbf,
                                                  u16* __restrict__ xb) {
    __shared__ __align__(16) u16 sB_[128][68];   // B [t'][n]
    __shared__ __align__(16) u16 sC_[128][68];   // C [t][n]
    __shared__ __align__(16) u16 sS[128][132];   // S' [t][t']
    __shared__ __align__(16) u16 sXT[128][36];   // X^T [p][k-tile]
    __shared__ float sdt[SEGT], sL[SEGT], sEL[SEGT], stmp[32];

    const int blk = blockIdx.x;
    const int seg = blk >> 7, b = (blk >> 4) & 7, h = blk & 15;
    const int tid = threadIdx.x;
    const int wave = tid >> 6, lane = tid & 63;
    const int quad = lane >> 4, lr = lane & 15;
    const int wm = wave & 1, wn = wave >> 1;
    const int t0 = seg * SEGT;

#pragma unroll
    for (int it = 0; it < 4; ++it) {
        int idx = tid + it * 256;
        int t = idx >> 3, c = (idx & 7) * 8;
        int r = (t0 + t) * B_SZ + b;
        *(uint4*)&sB_[t][c] = *(const uint4*)(BCm + (size_t)r * BCSTR + h * NSTATE + c);
        *(uint4*)&sC_[t][c] = *(const uint4*)(BCm + (size_t)r * BCSTR + 1024 + h * NSTATE + c);
    }
    if (tid < SEGT) sdt[tid] = dtv[((t0 + tid) * B_SZ + b) * NHEAD + h];
    else if (tid < 2 * SEGT) {
        int t = tid - SEGT;
        sL[t] = __logf(fmaxf(decayv[((t0 + t) * B_SZ + b) * NHEAD + h], 1e-30f));
    }
    __syncthreads();
    if (tid < 32) {
        float s = 0.f, v[4];
#pragma unroll
        for (int i = 0; i < 4; ++i) { s += sL[tid * 4 + i]; v[i] = s; }
        stmp[tid] = s;
#pragma unroll
        for (int i = 0; i < 4; ++i) sL[tid * 4 + i] = v[i];
    }
    __syncthreads();
    if (tid == 0) {
        float run = 0.f;
        for (int q = 0; q < 32; ++q) { float c2 = stmp[q]; stmp[q] = run; run += c2; }
    }
    __syncthreads();
    if (tid < 32) {
        float off = stmp[tid];
#pragma unroll
        for (int i = 0; i < 4; ++i) sL[tid * 4 + i] += off;
    }
    __syncthreads();
    if (tid < SEGT) sEL[tid] = __expf(sL[tid]);

    floatx4 accS[4][4];
#pragma unroll
    for (int i = 0; i < 4; i++)
#pragma unroll
        for (int j = 0; j < 4; j++)
#pragma unroll
            for (int r = 0; r < 4; r++) accS[i][j][r] = 0.f;
#pragma unroll
    for (int k0 = 0; k0 < 64; k0 += 32) {
        bf16x8 af[4], bfr[4];
#pragma unroll
        for (int i = 0; i < 4; i++)
            af[i] = *(const bf16x8*)&sB_[wm * 64 + i * 16 + lr][k0 + quad * 8];
#pragma unroll
        for (int j = 0; j < 4; j++)
            bfr[j] = *(const bf16x8*)&sC_[wn * 64 + j * 16 + lr][k0 + quad * 8];
#pragma unroll
        for (int i = 0; i < 4; i++)
#pragma unroll
            for (int j = 0; j < 4; j++)
                accS[i][j] = __builtin_amdgcn_mfma_f32_16x16x32_bf16(af[i], bfr[j], accS[i][j], 0, 0, 0);
    }
#pragma unroll
    for (int j = 0; j < 4; j++) {
        int tt = wn * 64 + j * 16 + lr;
        float Lt = sL[tt];
#pragma unroll
        for (int i = 0; i < 4; i++) {
#pragma unroll
            for (int r = 0; r < 4; r++) {
                int tp = wm * 64 + i * 16 + quad * 4 + r;
                float v = 0.f;
                if (tp <= tt) v = accS[i][j][r] * sdt[tp] * __expf(Lt - sL[tp]);
                sS[tt][tp] = f2bf(v);
            }
        }
    }

    floatx4 acc[4][4];
#pragma unroll
    for (int i = 0; i < 4; i++)
#pragma unroll
        for (int j = 0; j < 4; j++)
#pragma unroll
            for (int r = 0; r < 4; r++) acc[i][j][r] = 0.f;
    __syncthreads();
    if (seg > 0) {
        const u16* hbase = Hbf + (size_t)(seg - 1) * SLOT + (((size_t)b * NHEAD + h) * PDIM) * NSTATE;
#pragma unroll
        for (int k0 = 0; k0 < 64; k0 += 32) {
            bf16x8 af[4], bfr[4];
#pragma unroll
            for (int i = 0; i < 4; i++)
                af[i] = *(const bf16x8*)&sC_[wm * 64 + i * 16 + lr][k0 + quad * 8];
#pragma unroll
            for (int j = 0; j < 4; j++)
                bfr[j] = *(const bf16x8*)(hbase + (size_t)(wn * 64 + j * 16 + lr) * NSTATE + k0 + quad * 8);
#pragma unroll
            for (int i = 0; i < 4; i++)
#pragma unroll
                for (int j = 0; j < 4; j++)
                    acc[i][j] = __builtin_amdgcn_mfma_f32_16x16x32_bf16(af[i], bfr[j], acc[i][j], 0, 0, 0);
        }
#pragma unroll
        for (int i = 0; i < 4; i++) {
#pragma unroll
            for (int r = 0; r < 4; r++) {
                float el = sEL[wm * 64 + i * 16 + quad * 4 + r];
#pragma unroll
                for (int j = 0; j < 4; j++) acc[i][j][r] *= el;
            }
        }
    }

    const int px = tid & 127, koh = (tid >> 7) * 16;
    for (int kc = 0; kc < 128; kc += 32) {
        u16 xv[16];
#pragma unroll
        for (int j2 = 0; j2 < 16; ++j2) {
            int tp = kc + koh + j2;
            xv[j2] = xb[(size_t)((t0 + tp) * B_SZ + b) * D_IN + h * PDIM + px];
        }
        __syncthreads();
        *(uint4*)&sXT[px][koh]     = *(const uint4*)&xv[0];
        *(uint4*)&sXT[px][koh + 8] = *(const uint4*)&xv[8];
        __syncthreads();
        bf16x8 af[4], bfr[4];
#pragma unroll
        for (int i = 0; i < 4; i++)
            af[i] = *(const bf16x8*)&sS[wm * 64 + i * 16 + lr][kc + quad * 8];
#pragma unroll
        for (int j = 0; j < 4; j++)
            bfr[j] = *(const bf16x8*)&sXT[wn * 64 + j * 16 + lr][quad * 8];
#pragma unroll
        for (int i = 0; i < 4; i++)
#pragma unroll
            for (int j = 0; j < 4; j++)
                acc[i][j] = __builtin_amdgcn_mfma_f32_16x16x32_bf16(af[i], bfr[j], acc[i][j], 0, 0, 0);
    }

#pragma unroll
    for (int j = 0; j < 4; j++) {
        int p = wn * 64 + j * 16 + lr;
#pragma unroll
        for (int i = 0; i < 4; i++) {
#pragma unroll
            for (int r = 0; r < 4; r++) {
                int t = wm * 64 + i * 16 + quad * 4 + r;
                xb[(size_t)((t0 + t) * B_SZ + b) * D_IN + h * PDIM + p] = f2bf(acc[i][j][r]);
            }
        }
    }
}

// ---------------- launch ----------------
extern "C" void kernel_launch(void* const* d_in, const int* in_sizes, int n_in,
                              void* d_out, int out_size, void* d_ws, size_t ws_size,
                              hipStream_t stream) {
    const float* obs     = (const float*)d_in[0];
    const float* W_in    = (const float*)d_in[1];
    const float* b_in    = (const float*)d_in[2];
    const float* A_log   = (const float*)d_in[3];
    const float* dt_bias = (const float*)d_in[4];
    const float* W_dt    = (const float*)d_in[5];
    const float* W_B     = (const float*)d_in[6];
    const float* W_C     = (const float*)d_in[7];
    const float* W_yo    = (const float*)d_in[8];
    const float* b_yo    = (const float*)d_in[9];
    const float* W_head  = (const float*)d_in[10];
    const float* b_head  = (const float*)d_in[11];

    char* ws = (char*)d_ws;
    size_t o = 0;
    u16*   xb     = (u16*)(ws + o);   o += (size_t)ROWS * D_IN * 2;            // 16 MB (x, then y in-place)
    u16*   BCm    = (u16*)(ws + o);   o += (size_t)ROWS * BCSTR * 2;           // 17.8 MB (B | C | dtraw | pad)
    float* dtv    = (float*)(ws + o); o += (size_t)ROWS * NHEAD * 4;
    float* decayv = (float*)(ws + o); o += (size_t)ROWS * NHEAD * 4;
    u16*   zb     = (u16*)(ws + o);   o += (size_t)ROWS * NUNITS * 2;          // 2 MB
    float* Hseg   = (float*)(ws + o); o += (size_t)(NSEG - 1) * SLOT * 4;      // 12 MB
    u16*   Hbf    = (u16*)(ws + o);   o += (size_t)(NSEG - 1) * SLOT * 2;      // 6 MB
    u16*   obsb   = (u16*)(ws + o);   o += (size_t)ROWS * OBS_D * 2;           // 2 MB
    u16*   WinT   = (u16*)(ws + o);   o += (size_t)D_IN * OBS_D * 2;           // 1 MB
    u16*   WBCT   = (u16*)(ws + o);   o += (size_t)BCSTR * D_IN * 2;           // 8.9 MB
    u16*   WyoT   = (u16*)(ws + o);   o += (size_t)NUNITS * D_IN * 2;          // 1 MB
    u16*   WheadT = (u16*)(ws + o);   o += (size_t)NACT * NUNITS * 2;

    // zero-work launch of the harness-required symbol (kept referenced)
    ActorAgent_27625229647898_kernel<<<dim3(1), 256, 0, stream>>>((float*)d_out, 0, 0.f);

    // ---- all weight prep in one launch ----
    prep<<<dim3(160 + 5136), 256, 0, stream>>>(obs, W_dt, W_in, W_B, W_C, W_yo, W_head,
                                               obsb, WinT, WBCT, WyoT, WheadT);

    // ---- x = relu(obs @ W_in + b_in) -> bf16 ----
    gemm_bt128<1, 1, 1><<<dim3(32, 16), 256, 0, stream>>>(obsb, WinT, b_in, xb, ROWS, D_IN, OBS_D);
    // ---- B|C|dtraw projection (N = 2176, exactly 17 tiles) ----
    gemm_bt128<0, 1, 0><<<dim3(32, 17), 256, 0, stream>>>(xb, WBCT, (const float*)nullptr, BCm, ROWS, BCSTR, D_IN);
    // ---- dt = softplus(dtraw + dt_bias); decay = exp(-exp(A_log)*dt) ----
    dt_fix<<<dim3(256), 256, 0, stream>>>(BCm, dt_bias, A_log, dtv, decayv);
    // ---- scan: A) segment-local final states ----
    seg_state<<<dim3((NSEG - 1) * 128), 256, 0, stream>>>(xb, BCm, dtv, decayv, Hseg);
    //          B) prefix combine -> bf16 ----
    seg_prefix<<<dim3(512), 256, 0, stream>>>(Hseg, decayv, Hbf);
    //          C) fused S' + Y, in-place over xb ----
    chunk_scan<<<dim3(NSEG * 128), 256, 0, stream>>>(BCm, dtv, decayv, Hbf, xb);
    // ---- z = relu(y @ W_yo + b_yo) -> bf16 ----
    gemm_bt64<1, 1><<<dim3(64, 4), 256, 0, stream>>>(xb, WyoT, b_yo, zb, ROWS, NUNITS, D_IN);
    // ---- logits = z @ W_head + b_head -> d_out (fp32) ----
    gemm_bt64<0, 0><<<dim3(64, 1), 256, 0, stream>>>(zb, WheadT, b_head, (float*)d_out, ROWS, NACT, NUNITS);
}